// Round 8
// baseline (314.998 us; speedup 1.0000x reference)
//
#include <hip/hip_runtime.h>

// EfficientAttention: N=8, C=256, H=W=128 (L=16384), HEADS=8, hc=32
// out = x + att,  att[n,h,cv,l] = sum_ck (ctx[ck,cv]/S[ck]) * softmax_ck(q)[ck,l]
// ctx[ck,cv] = sum_l exp(k[ck,l]) * v[cv,l],  S[ck] = sum_l exp(k[ck,l])

typedef __attribute__((ext_vector_type(8))) short short8;
typedef __attribute__((ext_vector_type(4))) float f32x4;

#define NB     8
#define CCH    256
#define LSP    16384
#define NHEADS 8
#define HC     32
#define TPX    64     // pixels per tile
#define NT     8      // tiles per block -> 512 px/block, 256 blocks (1/CU)

__device__ __forceinline__ unsigned short f2bf(float f) {
  union { float f; unsigned u; } v; v.f = f;
  unsigned r = v.u + 0x7fffu + ((v.u >> 16) & 1u);   // RNE
  return (unsigned short)(r >> 16);
}
__device__ __forceinline__ unsigned cvt_pk_bf16(float lo, float hi) {
  unsigned r;
  asm("v_cvt_pk_bf16_f32 %0, %1, %2" : "=v"(r) : "v"(lo), "v"(hi));
  return r;   // low 16 = bf16(lo), high 16 = bf16(hi)
}
__device__ __forceinline__ void gload_lds16(const unsigned short* g, unsigned short* l) {
  __builtin_amdgcn_global_load_lds(
      (const __attribute__((address_space(1))) unsigned int*)g,
      (__attribute__((address_space(3))) unsigned int*)l, 16, 0, 0);
}

// ---------------- kernel 0: weights -> bf16 head-grouped [k;v;q], zero ctx/S ----------------
__global__ void k_prep(const float* __restrict__ Wk, const float* __restrict__ bk,
                       const float* __restrict__ Wq, const float* __restrict__ bq,
                       const float* __restrict__ Wv, const float* __restrict__ bv,
                       unsigned short* __restrict__ Wb, float* __restrict__ bb,
                       float* __restrict__ ctx, float* __restrict__ S) {
  int idx = blockIdx.x * 256 + threadIdx.x;
  if (idx < NHEADS * 96 * CCH) {
    int c = idx & (CCH - 1);
    int row = (idx >> 8) % 96;
    int h = idx / (96 * CCH);
    int ch = h * HC;
    float val;
    if (row < HC)          val = Wk[(ch + row) * CCH + c];
    else if (row < 2 * HC) val = Wv[(ch + row - HC) * CCH + c];
    else                   val = Wq[(ch + row - 2 * HC) * CCH + c];
    Wb[idx] = f2bf(val);
  }
  if (idx < NHEADS * 96) {
    int row = idx % 96, h = idx / 96, ch = h * HC;
    float val;
    if (row < HC)          val = bk[ch + row];
    else if (row < 2 * HC) val = bv[ch + row - HC];
    else                   val = bq[ch + row - 2 * HC];
    bb[idx] = val;
  }
  if (idx < NB * NHEADS * HC * HC) ctx[idx] = 0.f;
  if (idx < NB * NHEADS * HC)      S[idx]   = 0.f;
}

// ---------------- kernel 0b: x [n][c][l] f32 -> xT [n][l][c] bf16 ----------------
__global__ __launch_bounds__(256)
void k_transpose(const float* __restrict__ x, unsigned short* __restrict__ xT) {
  __shared__ float tile[64][65];
  int b = blockIdx.x;
  int ct = b & 3;
  int lt = (b >> 2) & 255;
  int n  = b >> 10;
  int c0 = ct * 64, l0 = lt * 64;
  int t = threadIdx.x;
  int li = t & 63, cr = t >> 6;
  const float* xp = x + (size_t)n * CCH * LSP;
#pragma unroll
  for (int i = 0; i < 16; ++i) {
    int ci = cr * 16 + i;
    tile[ci][li] = xp[(size_t)(c0 + ci) * LSP + l0 + li];
  }
  __syncthreads();
  int cp = t & 31, l8 = t >> 5;    // c-pair, l-octet
  unsigned short* xo = xT + ((size_t)n * LSP + l0) * CCH + c0;
#pragma unroll
  for (int i = 0; i < 8; ++i) {
    int l = l8 * 8 + i;
    unsigned pk = (unsigned)f2bf(tile[2 * cp][l]) | ((unsigned)f2bf(tile[2 * cp + 1][l]) << 16);
    *(unsigned*)&xo[(size_t)l * CCH + 2 * cp] = pk;
  }
}

// ---------------- kernel 1: fused QKV, 12 waves, W streamed from L2 ----------------
// grid 256 = 8n x 32 lgrp (512 px each); block 768 thr, 1 block/CU (LDS-pinned).
// VGPR cap fix: hipcc's default occupancy heuristic budgets 2 blocks/CU for a
// 768-thr kernel (6 waves/EU -> 84 VGPR cap, massive spill in rounds 5-7;
// launch_bounds arg2 was ignored/clamped). amdgpu_waves_per_eu(3,3) targets the
// real occupancy (one 12-wave block = 3 waves/EU) -> cap 512/3 ~= 170, no spill.
// waves 0-7 (KV, head=wid): stream head's k+v rows per-kk from L2, swapped MFMA
//   (lane = 4 contig px), exp -> wave-private strips, ctx MFMA accumulate in regs.
// waves 8-11 (Q): 2 heads' q rows streamed, normal MFMA, in-reg softmax,
//   softmaxed bf16 q stored [l][ck] direct to global.
// x staged via global_load_lds (KV waves), double buffer, vmcnt(0)+s_barrier per tile.
__global__ __launch_bounds__(768)
__attribute__((amdgpu_waves_per_eu(3, 3)))
void k_fused(const unsigned short* __restrict__ xT,
             const unsigned short* __restrict__ Wb, const float* __restrict__ bb,
             unsigned short* __restrict__ qbuf, float* __restrict__ ctx,
             float* __restrict__ S) {
  __shared__ unsigned short xt[2][TPX * CCH];   // 2 x 32 KiB, swizzled chunks
  __shared__ unsigned short ekv[8][2][32][72];  // 72 KiB strips (pitch 72: odd chunk stride)

  int bid = (int)blockIdx.x;
  int n = bid >> 5, lgrp = bid & 31;
  int l0 = lgrp * (TPX * NT);
  int tid = threadIdx.x;
  int wid = tid >> 6, lane = tid & 63;
  int r16 = lane & 15, kg = lane >> 4;

  const unsigned short* xTn = xT + ((size_t)n << 14) * CCH;

  // stage 64px x 256ch tile: 32 x 1KB pieces, 4 per KV wave; dest linear,
  // source chunk-XOR-swizzled (both-sides involution, rule 21)
  auto stage = [&](int buf, int tt) {
    int lb = l0 + tt * TPX;
#pragma unroll
    for (int i = 0; i < 4; ++i) {
      int f = wid * 4 + i;                  // 0..31
      int px = 2 * f + (lane >> 5);
      int cc = lane & 31;
      gload_lds16(xTn + ((size_t)(lb + px) << 8) + ((cc ^ (px & 7)) << 3),
                  &xt[buf][f * 512]);
    }
  };

  if (wid < 8) {
    stage(0, 0);
    asm volatile("s_waitcnt vmcnt(0)" ::: "memory");
  }
  __syncthreads();

  if (wid < 8) {
    // ================= KV waves =================
    int h = wid;
    const unsigned short* wrow = Wb + ((size_t)(h * 96 + r16) << 8) + kg * 8;
    float bias[4];
#pragma unroll
    for (int rf = 0; rf < 4; ++rf) bias[rf] = bb[h * 96 + rf * 16 + r16];

    f32x4 acc_ctx[2][2];
#pragma unroll
    for (int a = 0; a < 2; ++a)
#pragma unroll
      for (int b = 0; b < 2; ++b) acc_ctx[a][b] = (f32x4){0.f, 0.f, 0.f, 0.f};
    float sk0 = 0.f, sk1 = 0.f;

    int cur = 0;
    for (int t = 0; t < NT; ++t) {
      if (t + 1 < NT) stage(cur ^ 1, t + 1);

      f32x4 acc[4][4];   // [px-block][row-block]
#pragma unroll
      for (int a = 0; a < 4; ++a)
#pragma unroll
        for (int b = 0; b < 4; ++b) acc[a][b] = (f32x4){0.f, 0.f, 0.f, 0.f};
      const unsigned short* xb = &xt[cur][0];
#pragma unroll
      for (int kk = 0; kk < 8; ++kk) {
        short8 a0 = *(const short8*)&wrow[kk * 32];            // k rows 0-15
        short8 a1 = *(const short8*)&wrow[kk * 32 + 4096];     // k rows 16-31
        short8 a2 = *(const short8*)&wrow[kk * 32 + 8192];     // v rows 0-15
        short8 a3 = *(const short8*)&wrow[kk * 32 + 12288];    // v rows 16-31
        int ch0 = (((kk * 4 + kg) ^ (r16 & 7)) << 3);
#pragma unroll
        for (int pb = 0; pb < 4; ++pb) {
          short8 xf = *(const short8*)&xb[(pb * 16 + r16) * 256 + ch0];
          acc[pb][0] = __builtin_amdgcn_mfma_f32_16x16x32_bf16(xf, a0, acc[pb][0], 0, 0, 0);
          acc[pb][1] = __builtin_amdgcn_mfma_f32_16x16x32_bf16(xf, a1, acc[pb][1], 0, 0, 0);
          acc[pb][2] = __builtin_amdgcn_mfma_f32_16x16x32_bf16(xf, a2, acc[pb][2], 0, 0, 0);
          acc[pb][3] = __builtin_amdgcn_mfma_f32_16x16x32_bf16(xf, a3, acc[pb][3], 0, 0, 0);
        }
      }
      // scatter: lane holds (wrow = rf*16+r16, px = pb*16+kg*4+r) -> b64 strips
#pragma unroll
      for (int pb = 0; pb < 4; ++pb) {
#pragma unroll
        for (int rf = 0; rf < 4; ++rf) {
          float v0 = acc[pb][rf][0] + bias[rf];
          float v1 = acc[pb][rf][1] + bias[rf];
          float v2 = acc[pb][rf][2] + bias[rf];
          float v3 = acc[pb][rf][3] + bias[rf];
          if (rf < 2) {
            float e0 = __expf(v0), e1 = __expf(v1), e2 = __expf(v2), e3 = __expf(v3);
            if (rf == 0) sk0 += e0 + e1 + e2 + e3; else sk1 += e0 + e1 + e2 + e3;
            uint2 u = {cvt_pk_bf16(e0, e1), cvt_pk_bf16(e2, e3)};
            *(uint2*)&ekv[wid][0][rf * 16 + r16][pb * 16 + kg * 4] = u;
          } else {
            uint2 u = {cvt_pk_bf16(v0, v1), cvt_pk_bf16(v2, v3)};
            *(uint2*)&ekv[wid][1][(rf - 2) * 16 + r16][pb * 16 + kg * 4] = u;
          }
        }
      }
      // ctx += ek . v^T over this tile's 64 px (wave-private, no barrier needed)
#pragma unroll
      for (int ckf = 0; ckf < 2; ++ckf)
#pragma unroll
        for (int cvf = 0; cvf < 2; ++cvf)
#pragma unroll
          for (int ks = 0; ks < 2; ++ks) {
            short8 a = *(const short8*)&ekv[wid][0][ckf * 16 + r16][ks * 32 + kg * 8];
            short8 b = *(const short8*)&ekv[wid][1][cvf * 16 + r16][ks * 32 + kg * 8];
            acc_ctx[ckf][cvf] = __builtin_amdgcn_mfma_f32_16x16x32_bf16(a, b, acc_ctx[ckf][cvf], 0, 0, 0);
          }
      __builtin_amdgcn_sched_barrier(0);
      asm volatile("s_waitcnt vmcnt(0)" ::: "memory");   // af loads consumed; only stage DMA left
      __builtin_amdgcn_sched_barrier(0);
      __builtin_amdgcn_s_barrier();
      __builtin_amdgcn_sched_barrier(0);
      cur ^= 1;
    }
    // flush once per block
    float* cp = ctx + ((size_t)(n * NHEADS + h) << 10);
#pragma unroll
    for (int ckf = 0; ckf < 2; ++ckf)
#pragma unroll
      for (int cvf = 0; cvf < 2; ++cvf)
#pragma unroll
        for (int rr = 0; rr < 4; ++rr)
          atomicAdd(&cp[(ckf * 16 + kg * 4 + rr) * HC + cvf * 16 + r16], acc_ctx[ckf][cvf][rr]);
    {
      float s0 = sk0, s1 = sk1;
      s0 += __shfl_xor(s0, 16); s0 += __shfl_xor(s0, 32);
      s1 += __shfl_xor(s1, 16); s1 += __shfl_xor(s1, 32);
      if (kg == 0) {
        atomicAdd(&S[(n * NHEADS + h) * HC + r16], s0);
        atomicAdd(&S[(n * NHEADS + h) * HC + 16 + r16], s1);
      }
    }
  } else {
    // ================= Q waves =================
    int wq = wid - 8;
    // rf -> row base: head (wq*2 + (rf>>1)), q-row block (rf&1)
    const unsigned short* wq0 = Wb + ((size_t)(wq * 2 * 96 + 64 + r16) << 8) + kg * 8;
    float bias[4][4];
#pragma unroll
    for (int rf = 0; rf < 4; ++rf) {
      int hq = wq * 2 + (rf >> 1);
#pragma unroll
      for (int rr = 0; rr < 4; ++rr)
        bias[rf][rr] = bb[hq * 96 + 64 + (rf & 1) * 16 + kg * 4 + rr];
    }

    int cur = 0;
    for (int t = 0; t < NT; ++t) {
      int lb = l0 + t * TPX;
      f32x4 acc[4][4];   // [rf][px-block]
#pragma unroll
      for (int a = 0; a < 4; ++a)
#pragma unroll
        for (int b = 0; b < 4; ++b) acc[a][b] = (f32x4){0.f, 0.f, 0.f, 0.f};
      const unsigned short* xb = &xt[cur][0];
#pragma unroll
      for (int kk = 0; kk < 8; ++kk) {
        short8 a0 = *(const short8*)&wq0[kk * 32];             // h0 q rows 0-15
        short8 a1 = *(const short8*)&wq0[kk * 32 + 4096];      // h0 q rows 16-31
        short8 a2 = *(const short8*)&wq0[kk * 32 + 24576];     // h1 q rows 0-15
        short8 a3 = *(const short8*)&wq0[kk * 32 + 28672];     // h1 q rows 16-31
        int ch0 = (((kk * 4 + kg) ^ (r16 & 7)) << 3);
#pragma unroll
        for (int pb = 0; pb < 4; ++pb) {
          short8 xf = *(const short8*)&xb[(pb * 16 + r16) * 256 + ch0];
          acc[0][pb] = __builtin_amdgcn_mfma_f32_16x16x32_bf16(a0, xf, acc[0][pb], 0, 0, 0);
          acc[1][pb] = __builtin_amdgcn_mfma_f32_16x16x32_bf16(a1, xf, acc[1][pb], 0, 0, 0);
          acc[2][pb] = __builtin_amdgcn_mfma_f32_16x16x32_bf16(a2, xf, acc[2][pb], 0, 0, 0);
          acc[3][pb] = __builtin_amdgcn_mfma_f32_16x16x32_bf16(a3, xf, acc[3][pb], 0, 0, 0);
        }
      }
      // softmax over ck (logits bounded -> no max-subtraction) + b64 stores
#pragma unroll
      for (int hb = 0; hb < 2; ++hb) {
        int hq = wq * 2 + hb;
        unsigned short* qb = qbuf + (((size_t)(n * NHEADS + hq) * LSP + lb) << 5);
#pragma unroll
        for (int pb = 0; pb < 4; ++pb) {
          float vl[4], vh[4];
          float s = 0.f;
#pragma unroll
          for (int rr = 0; rr < 4; ++rr) {
            vl[rr] = __expf(acc[hb * 2][pb][rr] + bias[hb * 2][rr]);
            vh[rr] = __expf(acc[hb * 2 + 1][pb][rr] + bias[hb * 2 + 1][rr]);
            s += vl[rr] + vh[rr];
          }
          s += __shfl_xor(s, 16);
          s += __shfl_xor(s, 32);
          float inv = 1.f / s;
          uint2 ul = {cvt_pk_bf16(vl[0] * inv, vl[1] * inv), cvt_pk_bf16(vl[2] * inv, vl[3] * inv)};
          uint2 uh = {cvt_pk_bf16(vh[0] * inv, vh[1] * inv), cvt_pk_bf16(vh[2] * inv, vh[3] * inv)};
          size_t po = ((size_t)(pb * 16 + r16) << 5) + kg * 4;
          *(uint2*)&qb[po] = ul;
          *(uint2*)&qb[po + 16] = uh;
        }
      }
      __builtin_amdgcn_s_barrier();    // stores retire on their own; no vm wait
      cur ^= 1;
    }
  }
}

// ---------------- kernel 2: ctx/S, transpose, -> bf16 ----------------
__global__ void k_norm(const float* __restrict__ ctx, const float* __restrict__ S,
                       unsigned short* __restrict__ ctxT) {
  int idx = blockIdx.x * 256 + threadIdx.x;  // 65536 = [n][h][ck][cv]
  int cv = idx & 31, ck = (idx >> 5) & 31, nh = idx >> 10;
  float v = ctx[idx] / S[(nh << 5) + ck];
  ctxT[(nh << 10) + (cv << 5) + ck] = f2bf(v);
}

// ---------------- kernel 3: att = ctxT (32x32) x q_soft (32 x L) + residual ----------------
__global__ __launch_bounds__(256)
void k_att(const float* __restrict__ x, const unsigned short* __restrict__ qbuf,
           const unsigned short* __restrict__ ctxT, float* __restrict__ out) {
  int b = blockIdx.x;
  int lc = b & 63;
  int nh = b >> 6;
  int h = nh & 7, n = nh >> 3;
  int tid = threadIdx.x, wid = tid >> 6, lane = tid & 63;
  int r16 = lane & 15, kg = lane >> 4;
  int lw = lc * 256 + wid * 64;

  const unsigned short* cp = ctxT + ((size_t)nh << 10);
  short8 a0 = *(const short8*)&cp[(r16 << 5) + kg * 8];          // A[cv][ck], cv 0-15
  short8 a1 = *(const short8*)&cp[((16 + r16) << 5) + kg * 8];   // cv 16-31
  const unsigned short* qb = qbuf + (((size_t)nh * LSP) << 5);
  const float* xp = x   + ((size_t)n * CCH + (size_t)h * HC) * LSP;
  float*       op = out + ((size_t)n * CCH + (size_t)h * HC) * LSP;

#pragma unroll
  for (int t = 0; t < 4; ++t) {
    int l = lw + t * 16;
    short8 bf = *(const short8*)&qb[((size_t)(l + r16) << 5) + kg * 8];  // softmaxed q [l][ck]
    f32x4 d0 = {0, 0, 0, 0}, d1 = {0, 0, 0, 0};
    d0 = __builtin_amdgcn_mfma_f32_16x16x32_bf16(a0, bf, d0, 0, 0, 0);
    d1 = __builtin_amdgcn_mfma_f32_16x16x32_bf16(a1, bf, d1, 0, 0, 0);
#pragma unroll
    for (int r = 0; r < 4; ++r) {
      int cv = kg * 4 + r;
      int li = l + r16;
      op[(size_t)cv * LSP + li]        = d0[r] + xp[(size_t)cv * LSP + li];
      op[(size_t)(cv + 16) * LSP + li] = d1[r] + xp[(size_t)(cv + 16) * LSP + li];
    }
  }
}

extern "C" void kernel_launch(void* const* d_in, const int* in_sizes, int n_in,
                              void* d_out, int out_size, void* d_ws, size_t ws_size,
                              hipStream_t stream) {
  (void)in_sizes; (void)n_in; (void)out_size; (void)ws_size;
  const float* x  = (const float*)d_in[0];
  const float* Wk = (const float*)d_in[1];
  const float* bk = (const float*)d_in[2];
  const float* Wq = (const float*)d_in[3];
  const float* bq = (const float*)d_in[4];
  const float* Wv = (const float*)d_in[5];
  const float* bv = (const float*)d_in[6];
  float* out = (float*)d_out;

  char* ws = (char*)d_ws;
  unsigned short* Wb   = (unsigned short*)(ws + 0);          //   393216
  float*          bbp  = (float*)(ws + 393216);              //     3072
  float*          ctx  = (float*)(ws + 396288);              //   262144
  unsigned short* ctxT = (unsigned short*)(ws + 658432);     //   131072
  float*          S    = (float*)(ws + 789504);              //     8192
  unsigned short* qbuf = (unsigned short*)(ws + 797696);     // 67108864
  unsigned short* xT   = (unsigned short*)(ws + 67906560);   // 67108864 -> 135015424 total

  k_prep<<<768, 256, 0, stream>>>(Wk, bk, Wq, bq, Wv, bv, Wb, bbp, ctx, S);
  k_transpose<<<NB * 256 * 4, 256, 0, stream>>>(x, xT);
  k_fused<<<256, 768, 0, stream>>>(xT, Wb, bbp, qbuf, ctx, S);
  k_norm<<<256, 256, 0, stream>>>(ctx, S, ctxT);
  k_att<<<NB * NHEADS * 64, 256, 0, stream>>>(x, qbuf, ctxT, out);
}

// Round 9
// 216.571 us; speedup vs baseline: 1.4545x; 1.4545x over previous
//
#include <hip/hip_runtime.h>

// EfficientAttention: N=8, C=256, H=W=128 (L=16384), HEADS=8, hc=32
// out = x + att,  att[n,h,cv,l] = sum_ck (ctx[ck,cv]/S[ck]) * softmax_ck(q)[ck,l]
// ctx[ck,cv] = sum_l exp(k[ck,l]) * v[cv,l],  S[ck] = sum_l exp(k[ck,l])
//
// Empirical toolchain law (R4-R8): VGPR budget ~ inverse of block size
// (768thr->84 cap + spill, 256thr->~150 free). All register-heavy waves live
// in 256-thread blocks; W-fragments per wave capped at 64 VGPR (32 W-rows).

typedef __attribute__((ext_vector_type(8))) short short8;
typedef __attribute__((ext_vector_type(4))) float f32x4;

#define NB     8
#define CCH    256
#define LSP    16384
#define NHEADS 8
#define HC     32
#define GPX    1024   // pixels per group
#define TP2    32     // pixels per tile
#define NT2    32     // tiles per group

__device__ __forceinline__ unsigned short f2bf(float f) {
  union { float f; unsigned u; } v; v.f = f;
  unsigned r = v.u + 0x7fffu + ((v.u >> 16) & 1u);   // RNE
  return (unsigned short)(r >> 16);
}
__device__ __forceinline__ unsigned cvt_pk_bf16(float lo, float hi) {
  unsigned r;
  asm("v_cvt_pk_bf16_f32 %0, %1, %2" : "=v"(r) : "v"(lo), "v"(hi));
  return r;
}
__device__ __forceinline__ void gload_lds16(const unsigned short* g, unsigned short* l) {
  __builtin_amdgcn_global_load_lds(
      (const __attribute__((address_space(1))) unsigned int*)g,
      (__attribute__((address_space(3))) unsigned int*)l, 16, 0, 0);
}

// ---------------- kernel 0: weights -> bf16 head-grouped [k;v;q], zero ctx/S ----------------
__global__ void k_prep(const float* __restrict__ Wk, const float* __restrict__ bk,
                       const float* __restrict__ Wq, const float* __restrict__ bq,
                       const float* __restrict__ Wv, const float* __restrict__ bv,
                       unsigned short* __restrict__ Wb, float* __restrict__ bb,
                       float* __restrict__ ctx, float* __restrict__ S) {
  int idx = blockIdx.x * 256 + threadIdx.x;
  if (idx < NHEADS * 96 * CCH) {
    int c = idx & (CCH - 1);
    int row = (idx >> 8) % 96;
    int h = idx / (96 * CCH);
    int ch = h * HC;
    float val;
    if (row < HC)          val = Wk[(ch + row) * CCH + c];
    else if (row < 2 * HC) val = Wv[(ch + row - HC) * CCH + c];
    else                   val = Wq[(ch + row - 2 * HC) * CCH + c];
    Wb[idx] = f2bf(val);
  }
  if (idx < NHEADS * 96) {
    int row = idx % 96, h = idx / 96, ch = h * HC;
    float val;
    if (row < HC)          val = bk[ch + row];
    else if (row < 2 * HC) val = bv[ch + row - HC];
    else                   val = bq[ch + row - 2 * HC];
    bb[idx] = val;
  }
  if (idx < NB * NHEADS * HC * HC) ctx[idx] = 0.f;
  if (idx < NB * NHEADS * HC)      S[idx]   = 0.f;
}

// ---------------- kernel 0b: x [n][c][l] f32 -> xT [n][l][c] bf16 ----------------
__global__ __launch_bounds__(256)
void k_transpose(const float* __restrict__ x, unsigned short* __restrict__ xT) {
  __shared__ float tile[64][65];
  int b = blockIdx.x;
  int ct = b & 3;
  int lt = (b >> 2) & 255;
  int n  = b >> 10;
  int c0 = ct * 64, l0 = lt * 64;
  int t = threadIdx.x;
  int li = t & 63, cr = t >> 6;
  const float* xp = x + (size_t)n * CCH * LSP;
#pragma unroll
  for (int i = 0; i < 16; ++i) {
    int ci = cr * 16 + i;
    tile[ci][li] = xp[(size_t)(c0 + ci) * LSP + l0 + li];
  }
  __syncthreads();
  int cp = t & 31, l8 = t >> 5;
  unsigned short* xo = xT + ((size_t)n * LSP + l0) * CCH + c0;
#pragma unroll
  for (int i = 0; i < 8; ++i) {
    int l = l8 * 8 + i;
    unsigned pk = (unsigned)f2bf(tile[2 * cp][l]) | ((unsigned)f2bf(tile[2 * cp + 1][l]) << 16);
    *(unsigned*)&xo[(size_t)l * CCH + 2 * cp] = pk;
  }
}

// ---------------- kernel 1: fused QKV, 256-thr blocks, 6 types per px-group ----------------
// grid 768 = 6 types x 128 groups (8n x 16 pg of 1024 px); bid = type*128 + g
// (128 % 8 == 0 -> all 6 sibling blocks of a group share an XCD -> x L2-shared).
// types 0-3 (KV, heads type*2, type*2+1): wave = {k|v} of one head, 32 W-rows in
//   64 VGPR, swapped MFMA (lane = 4 contig px), exp/v -> pair strips, each wave
//   computes its ckf half of ctx via strip MFMA, accumulates in regs, atomics once.
// types 4-5 (Q): wave = one head's 32 q-rows, normal MFMA, in-reg softmax over ck
//   (2 shfl), softmaxed bf16 q stored [l][ck] direct to global.
// x staged 32px/tile via global_load_lds, triple buffer, counted vmcnt (never 0 mid-loop).
__global__ __launch_bounds__(256)
void k_fused(const unsigned short* __restrict__ xT,
             const unsigned short* __restrict__ Wb, const float* __restrict__ bb,
             unsigned short* __restrict__ qbuf, float* __restrict__ ctx,
             float* __restrict__ S) {
  __shared__ unsigned short xt[3][TP2 * CCH];        // 48 KiB (3 x 16 KiB)
  __shared__ unsigned short strips[2][2][32][40];    // 10 KiB: [headLocal][k|v][wrow][px]

  int bid = (int)blockIdx.x;
  int type = bid >> 7;           // 0..5
  int g = bid & 127;
  int n = g >> 4, pg = g & 15;
  int l0 = pg * GPX;
  int tid = threadIdx.x;
  int wid = tid >> 6, lane = tid & 63;
  int r16 = lane & 15, kg = lane >> 4;

  const unsigned short* xTn = xT + ((size_t)n << 14) * CCH;

  // stage 32px x 256ch tile (16 KiB = 16 pieces, 4 per wave); dest linear,
  // source chunk-XOR-swizzled (both-sides involution, rule 21)
  auto stage = [&](int buf, int tt) {
    int lb = l0 + tt * TP2;
#pragma unroll
    for (int i = 0; i < 4; ++i) {
      int f = wid * 4 + i;                  // 0..15
      int px = 2 * f + (lane >> 5);
      int cc = lane & 31;
      gload_lds16(xTn + ((size_t)(lb + px) << 8) + ((cc ^ (px & 7)) << 3),
                  &xt[buf][f * 512]);
    }
  };

  stage(0, 0);
  stage(1, 1);
  asm volatile("s_waitcnt vmcnt(4)" ::: "memory");   // buf0 done; buf1 in flight
  __builtin_amdgcn_sched_barrier(0);
  __builtin_amdgcn_s_barrier();
  __builtin_amdgcn_sched_barrier(0);

  if (type < 4) {
    // ================= KV blocks =================
    int hl = wid >> 1;             // head-local 0/1
    int kind = wid & 1;            // 0 = k, 1 = v
    int h = type * 2 + hl;
    const unsigned short* wp = Wb + ((size_t)(h * 96 + kind * 32 + r16) << 8) + kg * 8;
    short8 af[2][8];               // 64 VGPR: rows rf*16+r16 of this wave's 32 W-rows
#pragma unroll
    for (int rf = 0; rf < 2; ++rf)
#pragma unroll
      for (int kk = 0; kk < 8; ++kk)
        af[rf][kk] = *(const short8*)&wp[rf * 4096 + kk * 32];
    float bias[2];
#pragma unroll
    for (int rf = 0; rf < 2; ++rf) bias[rf] = bb[h * 96 + kind * 32 + rf * 16 + r16];

    f32x4 actx[2] = {{0.f,0.f,0.f,0.f},{0.f,0.f,0.f,0.f}};   // ckf = kind; [cvf]
    float sk0 = 0.f, sk1 = 0.f;

    int cur = 0;
    for (int t = 0; t < NT2; ++t) {
      if (t + 2 < NT2) {
        int b2 = cur + 2; if (b2 >= 3) b2 -= 3;
        stage(b2, t + 2);
      }
      const unsigned short* xb = &xt[cur][0];
      f32x4 acc[2][2];   // [pxf][rf]
#pragma unroll
      for (int a = 0; a < 2; ++a)
#pragma unroll
        for (int b = 0; b < 2; ++b) acc[a][b] = (f32x4){0.f, 0.f, 0.f, 0.f};
#pragma unroll
      for (int kk = 0; kk < 8; ++kk) {
        int ch0 = (((kk * 4 + kg) ^ (r16 & 7)) << 3);
        short8 x0 = *(const short8*)&xb[r16 * 256 + ch0];
        short8 x1 = *(const short8*)&xb[(16 + r16) * 256 + ch0];
        acc[0][0] = __builtin_amdgcn_mfma_f32_16x16x32_bf16(x0, af[0][kk], acc[0][0], 0, 0, 0);
        acc[0][1] = __builtin_amdgcn_mfma_f32_16x16x32_bf16(x0, af[1][kk], acc[0][1], 0, 0, 0);
        acc[1][0] = __builtin_amdgcn_mfma_f32_16x16x32_bf16(x1, af[0][kk], acc[1][0], 0, 0, 0);
        acc[1][1] = __builtin_amdgcn_mfma_f32_16x16x32_bf16(x1, af[1][kk], acc[1][1], 0, 0, 0);
      }
      // scatter: lane holds (wrow = rf*16+r16, px = pxf*16+kg*4+r) -> b64 strips
#pragma unroll
      for (int pxf = 0; pxf < 2; ++pxf) {
#pragma unroll
        for (int rf = 0; rf < 2; ++rf) {
          float v0 = acc[pxf][rf][0] + bias[rf];
          float v1 = acc[pxf][rf][1] + bias[rf];
          float v2 = acc[pxf][rf][2] + bias[rf];
          float v3 = acc[pxf][rf][3] + bias[rf];
          if (kind == 0) {
            float e0 = __expf(v0), e1 = __expf(v1), e2 = __expf(v2), e3 = __expf(v3);
            if (rf == 0) sk0 += e0 + e1 + e2 + e3; else sk1 += e0 + e1 + e2 + e3;
            uint2 u = {cvt_pk_bf16(e0, e1), cvt_pk_bf16(e2, e3)};
            *(uint2*)&strips[hl][0][rf * 16 + r16][pxf * 16 + kg * 4] = u;
          } else {
            uint2 u = {cvt_pk_bf16(v0, v1), cvt_pk_bf16(v2, v3)};
            *(uint2*)&strips[hl][1][rf * 16 + r16][pxf * 16 + kg * 4] = u;
          }
        }
      }
      asm volatile("s_waitcnt lgkmcnt(0)" ::: "memory");   // strip writes visible
      __builtin_amdgcn_sched_barrier(0);
      __builtin_amdgcn_s_barrier();
      __builtin_amdgcn_sched_barrier(0);
      // ctx += ek . v^T over this tile's 32 px; this wave owns ckf = kind
      {
        short8 a  = *(const short8*)&strips[hl][0][kind * 16 + r16][kg * 8];
        short8 b0 = *(const short8*)&strips[hl][1][r16][kg * 8];
        short8 b1 = *(const short8*)&strips[hl][1][16 + r16][kg * 8];
        actx[0] = __builtin_amdgcn_mfma_f32_16x16x32_bf16(a, b0, actx[0], 0, 0, 0);
        actx[1] = __builtin_amdgcn_mfma_f32_16x16x32_bf16(a, b1, actx[1], 0, 0, 0);
      }
      __builtin_amdgcn_sched_barrier(0);
      if (t + 2 < NT2) { asm volatile("s_waitcnt vmcnt(4)" ::: "memory"); }
      else             { asm volatile("s_waitcnt vmcnt(0)" ::: "memory"); }
      __builtin_amdgcn_sched_barrier(0);
      __builtin_amdgcn_s_barrier();
      __builtin_amdgcn_sched_barrier(0);
      cur = (cur == 2) ? 0 : cur + 1;
    }
    // flush once per block: ctx half-matrix (ckf = kind) + S rows (k-waves)
    float* cp = ctx + ((size_t)(n * NHEADS + h) << 10);
#pragma unroll
    for (int cvf = 0; cvf < 2; ++cvf)
#pragma unroll
      for (int r = 0; r < 4; ++r)
        atomicAdd(&cp[(kind * 16 + kg * 4 + r) * HC + cvf * 16 + r16], actx[cvf][r]);
    if (kind == 0) {
      float s0 = sk0, s1 = sk1;
      s0 += __shfl_xor(s0, 16); s0 += __shfl_xor(s0, 32);
      s1 += __shfl_xor(s1, 16); s1 += __shfl_xor(s1, 32);
      if (kg == 0) {
        atomicAdd(&S[(n * NHEADS + h) * HC + r16], s0);
        atomicAdd(&S[(n * NHEADS + h) * HC + 16 + r16], s1);
      }
    }
  } else {
    // ================= Q blocks =================
    int h = (type - 4) * 4 + wid;
    const unsigned short* wp = Wb + ((size_t)(h * 96 + 64 + r16) << 8) + kg * 8;
    short8 af[2][8];               // 64 VGPR: this head's 32 q-rows
#pragma unroll
    for (int rf = 0; rf < 2; ++rf)
#pragma unroll
      for (int kk = 0; kk < 8; ++kk)
        af[rf][kk] = *(const short8*)&wp[rf * 4096 + kk * 32];
    float bias[2][4];
#pragma unroll
    for (int rf = 0; rf < 2; ++rf)
#pragma unroll
      for (int rr = 0; rr < 4; ++rr)
        bias[rf][rr] = bb[h * 96 + 64 + rf * 16 + kg * 4 + rr];

    int cur = 0;
    for (int t = 0; t < NT2; ++t) {
      if (t + 2 < NT2) {
        int b2 = cur + 2; if (b2 >= 3) b2 -= 3;
        stage(b2, t + 2);
      }
      int lb = l0 + t * TP2;
      const unsigned short* xb = &xt[cur][0];
      f32x4 acc[2][2];   // [rf][pxf]
#pragma unroll
      for (int a = 0; a < 2; ++a)
#pragma unroll
        for (int b = 0; b < 2; ++b) acc[a][b] = (f32x4){0.f, 0.f, 0.f, 0.f};
#pragma unroll
      for (int kk = 0; kk < 8; ++kk) {
        int ch0 = (((kk * 4 + kg) ^ (r16 & 7)) << 3);
        short8 x0 = *(const short8*)&xb[r16 * 256 + ch0];
        short8 x1 = *(const short8*)&xb[(16 + r16) * 256 + ch0];
        acc[0][0] = __builtin_amdgcn_mfma_f32_16x16x32_bf16(af[0][kk], x0, acc[0][0], 0, 0, 0);
        acc[1][0] = __builtin_amdgcn_mfma_f32_16x16x32_bf16(af[1][kk], x0, acc[1][0], 0, 0, 0);
        acc[0][1] = __builtin_amdgcn_mfma_f32_16x16x32_bf16(af[0][kk], x1, acc[0][1], 0, 0, 0);
        acc[1][1] = __builtin_amdgcn_mfma_f32_16x16x32_bf16(af[1][kk], x1, acc[1][1], 0, 0, 0);
      }
      // softmax over ck (logits bounded -> no max-subtraction); store [l][ck] b64
#pragma unroll
      for (int pxf = 0; pxf < 2; ++pxf) {
        float e0[4], e1[4];
        float s = 0.f;
#pragma unroll
        for (int rr = 0; rr < 4; ++rr) {
          e0[rr] = __expf(acc[0][pxf][rr] + bias[0][rr]);
          e1[rr] = __expf(acc[1][pxf][rr] + bias[1][rr]);
          s += e0[rr] + e1[rr];
        }
        s += __shfl_xor(s, 16);
        s += __shfl_xor(s, 32);
        float inv = 1.f / s;
        unsigned short* qb = qbuf +
            (((size_t)(n * NHEADS + h) * LSP + lb + pxf * 16 + r16) << 5);
        uint2 u0 = {cvt_pk_bf16(e0[0] * inv, e0[1] * inv), cvt_pk_bf16(e0[2] * inv, e0[3] * inv)};
        uint2 u1 = {cvt_pk_bf16(e1[0] * inv, e1[1] * inv), cvt_pk_bf16(e1[2] * inv, e1[3] * inv)};
        *(uint2*)&qb[kg * 4]      = u0;
        *(uint2*)&qb[16 + kg * 4] = u1;
      }
      __builtin_amdgcn_sched_barrier(0);
      if (t + 2 < NT2)      { asm volatile("s_waitcnt vmcnt(8)" ::: "memory"); }
      else if (t + 1 < NT2) { asm volatile("s_waitcnt vmcnt(4)" ::: "memory"); }
      __builtin_amdgcn_sched_barrier(0);
      __builtin_amdgcn_s_barrier();
      __builtin_amdgcn_sched_barrier(0);
      cur = (cur == 2) ? 0 : cur + 1;
    }
  }
}

// ---------------- kernel 2: ctx/S, transpose, -> bf16 ----------------
__global__ void k_norm(const float* __restrict__ ctx, const float* __restrict__ S,
                       unsigned short* __restrict__ ctxT) {
  int idx = blockIdx.x * 256 + threadIdx.x;  // 65536 = [n][h][ck][cv]
  int cv = idx & 31, ck = (idx >> 5) & 31, nh = idx >> 10;
  float v = ctx[idx] / S[(nh << 5) + ck];
  ctxT[(nh << 10) + (cv << 5) + ck] = f2bf(v);
}

// ---------------- kernel 3: att = ctxT (32x32) x q_soft (32 x L) + residual ----------------
__global__ __launch_bounds__(256)
void k_att(const float* __restrict__ x, const unsigned short* __restrict__ qbuf,
           const unsigned short* __restrict__ ctxT, float* __restrict__ out) {
  int b = blockIdx.x;
  int lc = b & 63;
  int nh = b >> 6;
  int h = nh & 7, n = nh >> 3;
  int tid = threadIdx.x, wid = tid >> 6, lane = tid & 63;
  int r16 = lane & 15, kg = lane >> 4;
  int lw = lc * 256 + wid * 64;

  const unsigned short* cp = ctxT + ((size_t)nh << 10);
  short8 a0 = *(const short8*)&cp[(r16 << 5) + kg * 8];          // A[cv][ck], cv 0-15
  short8 a1 = *(const short8*)&cp[((16 + r16) << 5) + kg * 8];   // cv 16-31
  const unsigned short* qb = qbuf + (((size_t)nh * LSP) << 5);
  const float* xp = x   + ((size_t)n * CCH + (size_t)h * HC) * LSP;
  float*       op = out + ((size_t)n * CCH + (size_t)h * HC) * LSP;

#pragma unroll
  for (int t = 0; t < 4; ++t) {
    int l = lw + t * 16;
    short8 bf = *(const short8*)&qb[((size_t)(l + r16) << 5) + kg * 8];  // softmaxed q [l][ck]
    f32x4 d0 = {0, 0, 0, 0}, d1 = {0, 0, 0, 0};
    d0 = __builtin_amdgcn_mfma_f32_16x16x32_bf16(a0, bf, d0, 0, 0, 0);
    d1 = __builtin_amdgcn_mfma_f32_16x16x32_bf16(a1, bf, d1, 0, 0, 0);
#pragma unroll
    for (int r = 0; r < 4; ++r) {
      int cv = kg * 4 + r;
      int li = l + r16;
      op[(size_t)cv * LSP + li]        = d0[r] + xp[(size_t)cv * LSP + li];
      op[(size_t)(cv + 16) * LSP + li] = d1[r] + xp[(size_t)(cv + 16) * LSP + li];
    }
  }
}

extern "C" void kernel_launch(void* const* d_in, const int* in_sizes, int n_in,
                              void* d_out, int out_size, void* d_ws, size_t ws_size,
                              hipStream_t stream) {
  (void)in_sizes; (void)n_in; (void)out_size; (void)ws_size;
  const float* x  = (const float*)d_in[0];
  const float* Wk = (const float*)d_in[1];
  const float* bk = (const float*)d_in[2];
  const float* Wq = (const float*)d_in[3];
  const float* bq = (const float*)d_in[4];
  const float* Wv = (const float*)d_in[5];
  const float* bv = (const float*)d_in[6];
  float* out = (float*)d_out;

  char* ws = (char*)d_ws;
  unsigned short* Wb   = (unsigned short*)(ws + 0);          //   393216
  float*          bbp  = (float*)(ws + 393216);              //     3072
  float*          ctx  = (float*)(ws + 396288);              //   262144
  unsigned short* ctxT = (unsigned short*)(ws + 658432);     //   131072
  float*          S    = (float*)(ws + 789504);              //     8192
  unsigned short* qbuf = (unsigned short*)(ws + 797696);     // 67108864
  unsigned short* xT   = (unsigned short*)(ws + 67906560);   // 67108864 -> 135015424 total

  k_prep<<<768, 256, 0, stream>>>(Wk, bk, Wq, bq, Wv, bv, Wb, bbp, ctx, S);
  k_transpose<<<NB * 256 * 4, 256, 0, stream>>>(x, xT);
  k_fused<<<768, 256, 0, stream>>>(xT, Wb, bbp, qbuf, ctx, S);
  k_norm<<<256, 256, 0, stream>>>(ctx, S, ctxT);
  k_att<<<NB * NHEADS * 64, 256, 0, stream>>>(x, qbuf, ctxT, out);
}